// Round 1
// 126.399 us; speedup vs baseline: 1.0033x; 1.0033x over previous
//
#include <hip/hip_runtime.h>
#include <stdint.h>

// ---------------------------------------------------------------------------
// Patcher: bit-exact JAX threefry (partitionable scheme) + last-writer-wins
// composite. B=8, H=W=640, N=12 boxes, P=256 patch.
//
// R6: restructure. k_sums image blocks now FUSE the identity copy (read
// float4 -> accumulate -> write float4), so the background copy rides the
// mandatory mean-pass at streaming read+write rate. k_main is replaced by
// k_patch, which only visits each box's diagf x diagf square (<=113 < 128,
// since diag <= sqrt2*floor(200*0.4)), grid (16 tiles, 12 boxes, 8 images).
// Priority (last-writer-wins == highest box index) is preserved by skipping
// any pixel also covered by a higher-index valid box, using the exact same
// coverage predicate / float ops as before -> winner set identical ->
// output bit-identical to R5.
//
// ws doubles [0..1023]:  [b*120+i] img partials, [960+b*8+j] patch partials
// ws floats: [2048..2111] per-image wmul[3],_,badd[3],_ ; [2112..3647] box
// params (8*12*16).
// ---------------------------------------------------------------------------

#define IMG_ELEMS   1228800   // 640*640*3
#define NPIX        409600    // 640*640
#define PATCH_ELEMS 196608    // 256*256*3
#define WB_OFF 2048
#define BP_OFF 2112

#define TF_R(r) { x0 += x1; x1 = (x1 << r) | (x1 >> (32 - r)); x1 ^= x0; }

__device__ __forceinline__ void tf2x32(uint32_t k0, uint32_t k1,
                                       uint32_t c0, uint32_t c1,
                                       uint32_t& o0, uint32_t& o1) {
  uint32_t k2 = k0 ^ k1 ^ 0x1BD11BDAu;
  uint32_t x0 = c0 + k0, x1 = c1 + k1;
  TF_R(13) TF_R(15) TF_R(26) TF_R(6)
  x0 += k1; x1 += k2 + 1u;
  TF_R(17) TF_R(29) TF_R(16) TF_R(24)
  x0 += k2; x1 += k0 + 2u;
  TF_R(13) TF_R(15) TF_R(26) TF_R(6)
  x0 += k0; x1 += k1 + 3u;
  TF_R(17) TF_R(29) TF_R(16) TF_R(24)
  x0 += k1; x1 += k2 + 4u;
  TF_R(13) TF_R(15) TF_R(26) TF_R(6)
  x0 += k2; x1 += k0 + 5u;
  o0 = x0; o1 = x1;
}

__device__ __forceinline__ void split_key(uint32_t k0, uint32_t k1, uint32_t j,
                                          uint32_t& o0, uint32_t& o1) {
  tf2x32(k0, k1, 0u, j, o0, o1);
}

__device__ __forceinline__ uint32_t rbits32(uint32_t k0, uint32_t k1, uint32_t i) {
  uint32_t o0, o1;
  tf2x32(k0, k1, 0u, i, o0, o1);
  return o0 ^ o1;
}

__device__ __forceinline__ float u01(uint32_t bits) {
  return __uint_as_float((bits >> 9) | 0x3f800000u) - 1.0f;
}

// XLA ErfInv f32 (Giles) — value-level only (feeds wmul/badd normals)
__device__ __forceinline__ float erfinv_f(float x) {
  #pragma clang fp contract(off)
  float w = -log1pf(-(x * x));
  float p;
  if (w < 5.0f) {
    w = w - 2.5f;
    p = 2.81022636e-08f;
    p = 3.43273939e-07f + p * w;
    p = -3.5233877e-06f + p * w;
    p = -4.39150654e-06f + p * w;
    p = 0.00021858087f + p * w;
    p = -0.00125372503f + p * w;
    p = -0.00417768164f + p * w;
    p = 0.246640727f + p * w;
    p = 1.50140941f + p * w;
  } else {
    w = sqrtf(w) - 3.0f;
    p = -0.000200214257f;
    p = 0.000100950558f + p * w;
    p = 0.00134934322f + p * w;
    p = -0.00367342844f + p * w;
    p = 0.00573950773f + p * w;
    p = -0.0076224613f + p * w;
    p = 0.00943887047f + p * w;
    p = 1.00167406f + p * w;
    p = 2.83297682f + p * w;
  }
  return p * x;
}

// per-image wmul/badd channel values (identical formula everywhere)
__device__ __forceinline__ void wb_compute(int b, float* wm, float* bd) {
  #pragma clang fp contract(off)
  uint32_t ik0, ik1; split_key(0u, 42u, (uint32_t)b, ik0, ik1);
  uint32_t kw0, kw1; split_key(ik0, ik1, 0u, kw0, kw1);
  uint32_t kb0, kb1; split_key(ik0, ik1, 1u, kb0, kb1);
  const float lo  = __uint_as_float(0xBF7FFFFFu);   // nextafter(-1,0) f32
  const float SQ2 = (float)1.4142135623730951;
  for (int c = 0; c < 3; ++c) {
    float f  = u01(rbits32(kw0, kw1, (uint32_t)c));
    float u  = fmaxf(lo, __fadd_rn(__fmul_rn(f, 2.0f), lo));
    wm[c] = __fadd_rn(0.5f, __fmul_rn(0.1f, __fmul_rn(SQ2, erfinv_f(u))));
    float f2 = u01(rbits32(kb0, kb1, (uint32_t)c));
    float u2 = fmaxf(lo, __fadd_rn(__fmul_rn(f2, 2.0f), lo));
    bd[c] = __fmul_rn(0.01f, __fmul_rn(SQ2, erfinv_f(u2)));
  }
}

// ---------------------------------------------------------------------------
// K1: fused. bx<120: img-mean partial + IDENTITY COPY img->out (the copy
// rides the mandatory mean read-pass). bx==120: params block (ws writer).
// bx in 121..128: patch-adjust-sum partial (inline wmul/badd).
// ---------------------------------------------------------------------------
__global__ __launch_bounds__(256) void k_sums(const float4* __restrict__ img,
                                              float4* __restrict__ out4,
                                              const float4* __restrict__ patch,
                                              const float* __restrict__ boxes,
                                              const float* __restrict__ scale_p,
                                              float* __restrict__ wsf) {
  #pragma clang fp contract(off)
  int b = blockIdx.y;
  int bx = blockIdx.x;
  double* Pd = (double*)wsf;
  int tid = threadIdx.x;

  if (bx == 120) {
    if (b != 0) return;                 // params written once
    float scale = scale_p[0];
    if (tid < 8) {
      float wm[3], bd[3];
      wb_compute(tid, wm, bd);
      #pragma unroll
      for (int c = 0; c < 3; ++c) {
        wsf[WB_OFF + tid * 8 + c] = wm[c];
        wsf[WB_OFF + tid * 8 + 4 + c] = bd[c];
      }
    }
    if (tid >= 32 && tid < 128) {
      int t = tid - 32;
      int ib = t / 12, n = t % 12;
      uint32_t ik0, ik1; split_key(0u, 42u, (uint32_t)ib, ik0, ik1);
      uint32_t ks0, ks1; split_key(ik0, ik1, 2u, ks0, ks1);
      uint32_t bk0, bk1; split_key(ks0, ks1, (uint32_t)n, bk0, bk1);
      uint32_t kc10, kc11; split_key(bk0, bk1, 0u, kc10, kc11);
      uint32_t kc20, kc21; split_key(bk0, bk1, 1u, kc20, kc21);
      uint32_t ka0,  ka1;  split_key(bk0, bk1, 2u, ka0,  ka1);
      uint32_t kd0,  kd1;  split_key(bk0, bk1, 3u, kd0,  kd1);
      uint32_t kn0,  kn1;  split_key(bk0, bk1, 4u, kn0,  kn1);

      const float* bxp = boxes + (ib * 12 + n) * 4;
      float ymin = bxp[0], xmin = bxp[1], ymax = bxp[2], xmax = bxp[3];
      float h  = __fsub_rn(ymax, ymin);
      float ww = __fsub_rn(xmax, xmin);
      float longer = fmaxf(h, ww);
      float patch_size = floorf(__fmul_rn(longer, scale));
      float diag = fminf(__fmul_rn((float)1.41421356237, patch_size), 640.0f);
      float u1 = u01(rbits32(kc10, kc11, 0u));
      float u2 = u01(rbits32(kc20, kc21, 0u));
      float jy = __fmul_rn(__fmul_rn(__fsub_rn(u1, 0.5f), 0.2f), h);
      float jx = __fmul_rn(__fmul_rn(__fsub_rn(u2, 0.5f), 0.2f), ww);
      float oy = __fadd_rn(__fadd_rn(ymin, __fmul_rn(h, 0.5f)), jy);
      float ox = __fadd_rn(__fadd_rn(xmin, __fmul_rn(ww, 0.5f)), jx);
      float ymin_p = fmaxf(__fsub_rn(oy, __fmul_rn(diag, 0.5f)), 0.0f);
      float xmin_p = fmaxf(__fsub_rn(ox, __fmul_rn(diag, 0.5f)), 0.0f);
      ymin_p = (__fadd_rn(ymin_p, diag) > 640.0f) ? __fsub_rn(640.0f, diag) : ymin_p;
      xmin_p = (__fadd_rn(xmin_p, diag) > 640.0f) ? __fsub_rn(640.0f, diag) : xmin_p;
      float valid = (__fmul_rn(patch_size, patch_size) > 4.0f) ? 1.0f : 0.0f;
      float y0f = floorf(ymin_p), x0f = floorf(xmin_p);
      float phf = patch_size, diagf = floorf(diag);
      float top = floorf(__fmul_rn(__fsub_rn(diagf, phf), 0.5f));
      float ua = u01(rbits32(ka0, ka1, 0u));
      float angle = __fmul_rn(__fsub_rn(__fmul_rn(ua, 2.0f), 1.0f),
                              (float)0.3490658503988659);
      float ud = u01(rbits32(kd0, kd1, 0u));
      float delta = __fmul_rn(__fsub_rn(__fmul_rn(ud, 2.0f), 1.0f), 0.3f);
      float cc = __fmul_rn(__fsub_rn(diagf, 1.0f), 0.5f);
      float ca = (float)cos((double)angle);  // f64->f32 == correctly-rounded
      float sa = (float)sin((double)angle);
      float safe_ph = fmaxf(phf, 1.0f);
      float q = __fdiv_rn(256.0f, safe_ph);

      float* Pp = wsf + BP_OFF + (ib * 12 + n) * 16;
      Pp[0] = y0f;  Pp[1] = x0f;  Pp[2] = diagf; Pp[3] = phf;
      Pp[4] = top;  Pp[5] = cc;   Pp[6] = ca;    Pp[7] = sa;
      Pp[8] = delta; Pp[9] = valid;
      Pp[10] = __uint_as_float(kn0); Pp[11] = __uint_as_float(kn1);
      Pp[12] = q;
    }
    return;
  }

  double s = 0.0;
  int slot;
  if (bx < 120) {
    slot = b * 120 + bx;
    const float4* p = img + (size_t)b * (IMG_ELEMS / 4);
    float4* o = out4 + (size_t)b * (IMG_ELEMS / 4);
    const uint32_t stride = 120u * 256u;
    for (uint32_t i = bx * 256u + tid; i < (uint32_t)(IMG_ELEMS / 4); i += stride) {
      float4 v = p[i];
      o[i] = v;                       // fused background copy
      s += (double)v.x + (double)v.y + (double)v.z + (double)v.w;
    }
  } else {
    slot = 960 + b * 8 + (bx - 121);
    __shared__ float pwb[8];
    if (tid == 0) {
      float wm[3], bd[3];
      wb_compute(b, wm, bd);
      #pragma unroll
      for (int c = 0; c < 3; ++c) { pwb[c] = wm[c]; pwb[4 + c] = bd[c]; }
    }
    __syncthreads();
    float wm[3] = {pwb[0], pwb[1], pwb[2]};
    float bd[3] = {pwb[4], pwb[5], pwb[6]};
    const uint32_t stride = 8u * 256u;
    for (uint32_t i = (bx - 121u) * 256u + tid; i < (uint32_t)(PATCH_ELEMS / 4);
         i += stride) {
      float4 v = patch[i];
      uint32_t c = (4u * i) % 3u;
      float f[4] = {v.x, v.y, v.z, v.w};
      #pragma unroll
      for (int j = 0; j < 4; ++j) {
        float val = __fadd_rn(__fmul_rn(wm[c], f[j]), bd[c]);
        val = fminf(fmaxf(val, -1.0f), 1.0f);
        s += (double)val;
        c = (c == 2u) ? 0u : (c + 1u);
      }
    }
  }
  for (int off = 32; off > 0; off >>= 1) s += __shfl_down(s, off, 64);
  __shared__ double sd[4];
  if ((tid & 63) == 0) sd[tid >> 6] = s;
  __syncthreads();
  if (tid == 0) Pd[slot] = sd[0] + sd[1] + sd[2] + sd[3];
}

// ---------------------------------------------------------------------------
// K2: per-box composite. grid (16, 12, 8): blockIdx.z = image, .y = box n,
// .x = tile over the 128-wide padded diagf x diagf square (diagf <= 113 here
// since diag <= sqrt2*floor(200*0.4) = 113). Each thread: 4 px, same row.
// A pixel is written iff box n covers it (inside & src_ok & valid) AND no
// higher-index valid box covers it (identical predicate/float ops as the
// old winner search, so the winner set is bit-identical). Uncovered pixels
// keep K1's copy.
// ---------------------------------------------------------------------------
__global__ __launch_bounds__(256) void k_patch(const float* __restrict__ wsf,
                                               const float* __restrict__ patch,
                                               float* __restrict__ out) {
  #pragma clang fp contract(off)
  __shared__ float bp[192];
  __shared__ float s_dm;
  __shared__ double s_tot[2];
  int b = blockIdx.z;
  int n = blockIdx.y;
  int tid = threadIdx.x;
  const double* Pd = (const double*)wsf;
  const float* params = wsf + BP_OFF;
  if (tid < 192) bp[tid] = params[b * 192 + tid];
  if (tid >= 64 && tid < 128) {          // wave 1: image partials (120)
    int i = tid - 64;
    double s = Pd[b * 120 + i] + ((i + 64 < 120) ? Pd[b * 120 + i + 64] : 0.0);
    for (int off = 32; off > 0; off >>= 1) s += __shfl_down(s, off, 64);
    if (i == 0) s_tot[0] = s;
  }
  if (tid >= 128 && tid < 192) {         // wave 2: patch partials (8)
    int j = tid - 128;
    double s = (j < 8) ? Pd[960 + b * 8 + j] : 0.0;
    for (int off = 32; off > 0; off >>= 1) s += __shfl_down(s, off, 64);
    if (j == 0) s_tot[1] = s;
  }
  __syncthreads();
  if (tid == 0) {
    float mi = (float)(s_tot[0] / (double)IMG_ELEMS);
    float mp = (float)(s_tot[1] / (double)PATCH_ELEMS);
    s_dm = __fsub_rn(mi, mp);
  }
  __syncthreads();

  const float* Pp = &bp[n * 16];
  if (Pp[9] == 0.0f) return;             // invalid box: writes nothing
  float diagf = Pp[2];
  int idx = blockIdx.x * 1024 + tid * 4; // 128-wide padded square
  int u = idx >> 7;
  int v0 = idx & 127;
  float uf = (float)u;
  if (uf >= diagf) return;               // row outside square

  float y0f = Pp[0], x0f = Pp[1];
  int y = (int)y0f + u;
  float yf = (float)y;                   // == y0f + uf exactly (ints < 2^24)
  float cc = Pp[5], ca = Pp[6], sa = Pp[7];
  float top = Pp[4], phf = Pp[3];
  float ph1 = __fsub_rn(phf, 1.0f);
  float q = Pp[12], delta = Pp[8];
  uint32_t kn0 = __float_as_uint(Pp[10]), kn1 = __float_as_uint(Pp[11]);
  float dm = s_dm;
  const float* wb = wsf + WB_OFF + b * 8;
  float uc = __fsub_rn(uf, cc);

  #pragma unroll
  for (int j = 0; j < 4; ++j) {
    int vi = v0 + j;
    float vf = (float)vi;
    if (vf >= diagf) continue;           // col outside square (inside test)
    // rotation (identical op sequence to R5 winner search)
    float vc = __fsub_rn(vf, cc);
    float sv = __fadd_rn(__fsub_rn(__fmul_rn(ca, vc), __fmul_rn(sa, uc)), cc);
    float su = __fadd_rn(__fadd_rn(__fmul_rn(sa, vc), __fmul_rn(ca, uc)), cc);
    float ry = __fsub_rn(su, top);
    float rx = __fsub_rn(sv, top);
    if (!(ry >= 0.0f && ry <= ph1 && rx >= 0.0f && rx <= ph1)) continue;

    int x = (int)x0f + vi;
    float xf = (float)x;
    // priority: skip if any higher-index valid box also covers this pixel
    bool taken = false;
    for (int m = 11; m > n; --m) {
      const float* Pm = &bp[m * 16];
      if (Pm[9] == 0.0f) continue;
      float um = __fsub_rn(yf, Pm[0]);
      float vm = __fsub_rn(xf, Pm[1]);
      float dgm = Pm[2];
      if (!(um >= 0.0f && um < dgm && vm >= 0.0f && vm < dgm)) continue;
      float ccm = Pm[5], cam = Pm[6], sam = Pm[7];
      float vcm = __fsub_rn(vm, ccm), ucm = __fsub_rn(um, ccm);
      float svm = __fadd_rn(__fsub_rn(__fmul_rn(cam, vcm), __fmul_rn(sam, ucm)), ccm);
      float sum_ = __fadd_rn(__fadd_rn(__fmul_rn(sam, vcm), __fmul_rn(cam, ucm)), ccm);
      float rym = __fsub_rn(sum_, Pm[4]);
      float rxm = __fsub_rn(svm, Pm[4]);
      float phm1 = __fsub_rn(Pm[3], 1.0f);
      if (rym >= 0.0f && rym <= phm1 && rxm >= 0.0f && rxm <= phm1) {
        taken = true; break;
      }
    }
    if (taken) continue;

    // value (identical op sequence to R5 winner body)
    float py = __fsub_rn(__fmul_rn(__fadd_rn(ry, 0.5f), q), 0.5f);
    float px = __fsub_rn(__fmul_rn(__fadd_rn(rx, 0.5f), q), 0.5f);
    float fy = floorf(py), fx = floorf(px);
    float wy = __fsub_rn(py, fy), wx = __fsub_rn(px, fx);
    int y0i = min(max((int)fy, 0), 255);
    int x0i = min(max((int)fx, 0), 255);
    int y1i = min(y0i + 1, 255);
    int x1i = min(x0i + 1, 255);
    int i00 = (y0i * 256 + x0i) * 3, i01 = (y0i * 256 + x1i) * 3;
    int i10 = (y1i * 256 + x0i) * 3, i11 = (y1i * 256 + x1i) * 3;
    float omwx = __fsub_rn(1.0f, wx), omwy = __fsub_rn(1.0f, wy);
    int pix = y * 640 + x;
    size_t obase = ((size_t)b * NPIX + (size_t)pix) * 3u;
    #pragma unroll
    for (int ch = 0; ch < 3; ++ch) {
      float wmc = wb[ch], bdc = wb[4 + ch];
      float v00 = fminf(fmaxf(__fadd_rn(fminf(fmaxf(__fadd_rn(__fmul_rn(wmc, patch[i00 + ch]), bdc), -1.0f), 1.0f), dm), -1.0f), 1.0f);
      float v01 = fminf(fmaxf(__fadd_rn(fminf(fmaxf(__fadd_rn(__fmul_rn(wmc, patch[i01 + ch]), bdc), -1.0f), 1.0f), dm), -1.0f), 1.0f);
      float v10 = fminf(fmaxf(__fadd_rn(fminf(fmaxf(__fadd_rn(__fmul_rn(wmc, patch[i10 + ch]), bdc), -1.0f), 1.0f), dm), -1.0f), 1.0f);
      float v11 = fminf(fmaxf(__fadd_rn(fminf(fmaxf(__fadd_rn(__fmul_rn(wmc, patch[i11 + ch]), bdc), -1.0f), 1.0f), dm), -1.0f), 1.0f);
      float t_ = __fadd_rn(__fmul_rn(omwx, v00), __fmul_rn(wx, v01));
      float b_ = __fadd_rn(__fmul_rn(omwx, v10), __fmul_rn(wx, v11));
      float bil = __fadd_rn(__fmul_rn(omwy, t_), __fmul_rn(wy, b_));
      uint32_t ni = (uint32_t)pix * 3u + (uint32_t)ch;
      float nf = u01(rbits32(kn0, kn1, ni));
      float noise = fmaxf(-0.01f, __fadd_rn(__fmul_rn(nf, 0.02f), -0.01f));
      float val = __fadd_rn(__fadd_rn(bil, noise), delta);
      out[obase + ch] = fminf(fmaxf(val, -1.0f), 1.0f);
    }
  }
}

// ---------------------------------------------------------------------------
extern "C" void kernel_launch(void* const* d_in, const int* in_sizes, int n_in,
                              void* d_out, int out_size, void* d_ws, size_t ws_size,
                              hipStream_t stream) {
  const float* images = (const float*)d_in[0];
  const float* boxes  = (const float*)d_in[1];
  const float* patch  = (const float*)d_in[2];
  const float* scale  = (const float*)d_in[3];
  float* wsf = (float*)d_ws;

  hipLaunchKernelGGL(k_sums, dim3(129, 8), dim3(256), 0, stream,
                     (const float4*)images, (float4*)d_out,
                     (const float4*)patch, boxes, scale, wsf);
  hipLaunchKernelGGL(k_patch, dim3(16, 12, 8), dim3(256), 0, stream,
                     wsf, patch, (float*)d_out);
}